// Round 8
// baseline (146.542 us; speedup 1.0000x reference)
//
#include <hip/hip_runtime.h>
#include <hip/hip_bf16.h>
#include <math.h>

constexpr int Bz = 4, Cc = 64, Hh = 128, Ww = 128, Kk = 9;
constexpr int HW = Hh * Ww;              // 16384
constexpr float EPSf = 1e-5f;
constexpr int CK = Cc * Kk;              // 576

typedef __attribute__((ext_vector_type(8))) short short8;
typedef __attribute__((ext_vector_type(4))) float f32x4;

__device__ __forceinline__ ushort f32_to_bf16(float f) {
    uint u = __float_as_uint(f);
    return (ushort)((u + 0x7fffu + ((u >> 16) & 1u)) >> 16);   // RNE
}

__device__ __forceinline__ short8 pack8(float a0, float a1, float a2, float a3,
                                        float a4, float a5, float a6, float a7) {
    union { short8 s; uint u[4]; } r;
    float2 p; __hip_bfloat162 b;
    p.x = a0; p.y = a1; b = __float22bfloat162_rn(p); r.u[0] = *reinterpret_cast<uint*>(&b);
    p.x = a2; p.y = a3; b = __float22bfloat162_rn(p); r.u[1] = *reinterpret_cast<uint*>(&b);
    p.x = a4; p.y = a5; b = __float22bfloat162_rn(p); r.u[2] = *reinterpret_cast<uint*>(&b);
    p.x = a6; p.y = a7; b = __float22bfloat162_rn(p); r.u[3] = *reinterpret_cast<uint*>(&b);
    return r.s;
}

// ---- weight fragments (deform + offset-conv) in one launch ----
__global__ void frag_kernel(const float* __restrict__ w1, const float* __restrict__ w2,
                            const float* __restrict__ ow1, const float* __restrict__ ow2,
                            ushort* __restrict__ wA1, ushort* __restrict__ wA2,
                            ushort* __restrict__ oA1, ushort* __restrict__ oA2) {
    int tid = blockIdx.x * 256 + threadIdx.x;     // 2*36864 + 2*18432 = 110592
    if (tid >= 110592) return;
    const float* src; ushort* dst; int e; int cout;
    if (tid < 36864)        { src = w1;  dst = wA1; e = tid;         cout = 64; }
    else if (tid < 73728)   { src = w2;  dst = wA2; e = tid - 36864; cout = 64; }
    else if (tid < 92160)   { src = ow1; dst = oA1; e = tid - 73728; cout = 18; }
    else                    { src = ow2; dst = oA2; e = tid - 92160; cout = 18; }
    int j = e & 7, l = (e >> 3) & 63, kk = (e >> 9) % 18, wo = e / 9216;
    int oc = wo * 16 + (l & 15);
    int kidx = kk * 32 + ((l >> 4) * 8) + j;
    int tap = kidx >> 6, c = kidx & 63;
    dst[e] = (oc < cout) ? f32_to_bf16(src[oc * CK + c * 9 + tap]) : (ushort)0;
}

// ---- NCHW fp32 -> NHWC bf16 (tiled transpose), for x only ----
__global__ __launch_bounds__(256)
void nhwc_kernel(const float* __restrict__ src, ushort* __restrict__ dst) {
    __shared__ float s_t[64][65];
    int blk = blockIdx.x;                 // Bz * (HW/64) = 1024
    int p0 = (blk & 255) * 64;
    int b = blk >> 8;
    int t = threadIdx.x;
    int tp = t & 63;
    #pragma unroll
    for (int i = 0; i < 16; i++) {
        int c = i * 4 + (t >> 6);
        s_t[c][tp] = src[((size_t)(b * 64 + c)) * HW + p0 + tp];
    }
    __syncthreads();
    #pragma unroll
    for (int i = 0; i < 16; i++) {
        int pl = i * 4 + (t >> 6);
        dst[((size_t)b * HW + p0 + pl) * 64 + tp] = f32_to_bf16(s_t[tp][pl]);
    }
}

// ---- fully-fused per-wave kernel: each WAVE owns 16 px end-to-end ----
// offset-conv (36 MFMA) -> coords -> streamed gather+blend+deform MFMA (72)
// -> stores + in-wave GN partial. Only 2 barriers; no sample staging in LDS.
__global__ __launch_bounds__(256, 4)
void deform_fused_kernel(const ushort* __restrict__ xnh, const ushort* __restrict__ wA,
                         const ushort* __restrict__ owA, const float* __restrict__ bias,
                         const float* __restrict__ obias, float* __restrict__ y,
                         float* __restrict__ part) {
    __shared__ float  s_off[4][16 * 18];   // per-wave offset-conv output
    __shared__ uint   s_yx[4][144];        // per-wave packed (y0,x0) per (px,tap)
    __shared__ float2 s_w2[4][144];        // per-wave (wy,wx) per (px,tap)

    int t = threadIdx.x;
    int wv = t >> 6, lane = t & 63;
    int gid = blockIdx.x * 4 + wv;         // 4096 waves: b(2) | h(7) | wt(3)
    int wt = gid & 7;
    int h  = (gid >> 3) & 127;
    int b  = gid >> 10;
    int w0 = wt * 16;
    int g = lane >> 4, li = lane & 15;
    const ushort* xnb = xnh + (size_t)b * HW * 64;
    const char* xnc = reinterpret_cast<const char*>(xnb);

    // ---- phase A: offset conv, whole K per wave, 2 oc-tiles ----
    {
        f32x4 oa0, oa1;
        #pragma unroll
        for (int r = 0; r < 4; r++) {
            oa0[r] = obias[g * 4 + r];
            oa1[r] = (g == 0 && r < 2) ? obias[16 + r] : 0.f;
        }
        const short8* owf = reinterpret_cast<const short8*>(owA) + lane;
        #pragma unroll
        for (int kk = 0; kk < 18; kk++) {
            int tap = kk >> 1;
            int ky = tap / 3 - 1, kx = tap - (tap / 3) * 3 - 1;
            int cb = (kk & 1) * 64 + g * 16;            // channel byte offset
            int gy = h + ky, gx = w0 + li + kx;
            bool valid = ((unsigned)gy < 128u) && ((unsigned)gx < 128u);
            short8 bf = {0, 0, 0, 0, 0, 0, 0, 0};
            if (valid)
                bf = *reinterpret_cast<const short8*>(xnc + ((((gy << 7) + gx) << 7) + cb));
            oa0 = __builtin_amdgcn_mfma_f32_16x16x32_bf16(owf[(0 * 18 + kk) * 64], bf, oa0, 0, 0, 0);
            oa1 = __builtin_amdgcn_mfma_f32_16x16x32_bf16(owf[(1 * 18 + kk) * 64], bf, oa1, 0, 0, 0);
        }
        #pragma unroll
        for (int r = 0; r < 4; r++) {
            s_off[wv][li * 18 + g * 4 + r] = oa0[r];    // oc 0..15
            if (g == 0 && r < 2) s_off[wv][li * 18 + 16 + r] = oa1[r];
        }
    }
    __syncthreads();

    // ---- phase 0: coords for this wave's 144 (px,tap) units ----
    #pragma unroll
    for (int it = 0; it < 3; it++) {
        int u = it * 64 + lane;
        if (u < 144) {
            int px = u / 9, k = u - px * 9;
            int ky = k / 3 - 1, kx = k - (k / 3) * 3 - 1;
            float ody = s_off[wv][px * 18 + 2 * k];
            float odx = s_off[wv][px * 18 + 2 * k + 1];
            float cy = (float)(h + ky) + ody;
            float cx = (float)(w0 + px + kx) + odx;
            float fy = floorf(cy), fx = floorf(cx);
            int y0 = (int)fy, x0 = (int)fx;
            s_yx[wv][u] = (uint)(y0 & 0xffff) | ((uint)x0 << 16);
            float2 wv2; wv2.x = cy - fy; wv2.y = cx - fx;
            s_w2[wv][u] = wv2;
        }
    }
    __syncthreads();

    // ---- main: streamed gather + blend + deform MFMA, 9 iterations ----
    f32x4 acc[4];
    #pragma unroll
    for (int tile = 0; tile < 4; tile++) {
        const float* bp = bias + tile * 16 + g * 4;
        acc[tile].x = bp[0]; acc[tile].y = bp[1]; acc[tile].z = bp[2]; acc[tile].w = bp[3];
    }
    const short8* wf = reinterpret_cast<const short8*>(wA) + lane;
    int cbyte = g * 16;                      // byte offset of this lane's 8 channels

    for (int tt = 0; tt < 9; tt++) {
        int u = li * 9 + tt;
        uint yx = s_yx[wv][u];               // broadcast across g-lanes
        float2 wv2 = s_w2[wv][u];
        int y0 = (short)(yx & 0xffffu);
        int x0 = (short)(yx >> 16);
        float wy = wv2.x, wx = wv2.y;
        int y1 = y0 + 1, x1 = x0 + 1;
        bool vy0 = (unsigned)y0 < 128u, vy1 = (unsigned)y1 < 128u;
        bool vx0 = (unsigned)x0 < 128u, vx1 = (unsigned)x1 < 128u;
        int yc0 = min(max(y0, 0), 127), yc1 = min(max(y1, 0), 127);
        int xc0 = min(max(x0, 0), 127), xc1 = min(max(x1, 0), 127);
        uint a00 = (uint)(((yc0 << 7) + xc0) << 7) + cbyte;
        uint a01 = (uint)(((yc0 << 7) + xc1) << 7) + cbyte;
        uint a10 = (uint)(((yc1 << 7) + xc0) << 7) + cbyte;
        uint a11 = (uint)(((yc1 << 7) + xc1) << 7) + cbyte;
        float w00 = (vy0 && vx0) ? (1.f - wy) * (1.f - wx) : 0.f;
        float w01 = (vy0 && vx1) ? (1.f - wy) * wx : 0.f;
        float w10 = (vy1 && vx0) ? wy * (1.f - wx) : 0.f;
        float w11 = (vy1 && vx1) ? wy * wx : 0.f;
        // 8 corner loads: lo = channels g*8.., hi = channels 32+g*8..
        uint4 L00 = *reinterpret_cast<const uint4*>(xnc + a00);
        uint4 L01 = *reinterpret_cast<const uint4*>(xnc + a01);
        uint4 L10 = *reinterpret_cast<const uint4*>(xnc + a10);
        uint4 L11 = *reinterpret_cast<const uint4*>(xnc + a11);
        uint4 H00 = *reinterpret_cast<const uint4*>(xnc + a00 + 64);
        uint4 H01 = *reinterpret_cast<const uint4*>(xnc + a01 + 64);
        uint4 H10 = *reinterpret_cast<const uint4*>(xnc + a10 + 64);
        uint4 H11 = *reinterpret_cast<const uint4*>(xnc + a11 + 64);
        #define LO(u) __uint_as_float((u) << 16)
        #define HI(u) __uint_as_float((u) & 0xffff0000u)
        #define BLEND(e) (fmaf(w11, LO(L11.e), fmaf(w10, LO(L10.e), fmaf(w01, LO(L01.e), w00 * LO(L00.e)))))
        #define BLENDH(e) (fmaf(w11, HI(L11.e), fmaf(w10, HI(L10.e), fmaf(w01, HI(L01.e), w00 * HI(L00.e)))))
        #define BLEND2(e) (fmaf(w11, LO(H11.e), fmaf(w10, LO(H10.e), fmaf(w01, LO(H01.e), w00 * LO(H00.e)))))
        #define BLEND2H(e) (fmaf(w11, HI(H11.e), fmaf(w10, HI(H10.e), fmaf(w01, HI(H01.e), w00 * HI(H00.e)))))
        short8 fa = pack8(BLEND(x), BLENDH(x), BLEND(y), BLENDH(y),
                          BLEND(z), BLENDH(z), BLEND(w), BLENDH(w));
        short8 fb = pack8(BLEND2(x), BLEND2H(x), BLEND2(y), BLEND2H(y),
                          BLEND2(z), BLEND2H(z), BLEND2(w), BLEND2H(w));
        #undef LO
        #undef HI
        #undef BLEND
        #undef BLENDH
        #undef BLEND2
        #undef BLEND2H
        #pragma unroll
        for (int tile = 0; tile < 4; tile++) {
            acc[tile] = __builtin_amdgcn_mfma_f32_16x16x32_bf16(
                wf[(tile * 18 + 2 * tt) * 64], fa, acc[tile], 0, 0, 0);
            acc[tile] = __builtin_amdgcn_mfma_f32_16x16x32_bf16(
                wf[(tile * 18 + 2 * tt + 1) * 64], fb, acc[tile], 0, 0, 0);
        }
    }

    // ---- epilogue: stores + in-wave GN partial ----
    float s = 0.f, s2 = 0.f;
    size_t pbase = (size_t)(b * 64) * HW + h * Ww + w0 + li;
    #pragma unroll
    for (int tile = 0; tile < 4; tile++) {
        #pragma unroll
        for (int r = 0; r < 4; r++) {
            float v = acc[tile][r];
            y[pbase + (size_t)(tile * 16 + g * 4 + r) * HW] = v;
            s += v; s2 += v * v;
        }
    }
    #pragma unroll
    for (int o = 32; o > 0; o >>= 1) {
        s  += __shfl_down(s, o);
        s2 += __shfl_down(s2, o);
    }
    if (lane == 0) { part[gid * 2] = s; part[gid * 2 + 1] = s2; }
}

// shared per-block reduction of one sample's 1024 partial pairs -> (mean, rsqrt)
__device__ __forceinline__ void gn_reduce_stats(const float* __restrict__ part, int b,
                                                int t, float& m_out, float& rs_out) {
    __shared__ float ls[4][2];
    __shared__ float s_ms[2];
    int base = b * 1024 + t;
    float s  = part[base * 2]            + part[(base + 256) * 2]
             + part[(base + 512) * 2]    + part[(base + 768) * 2];
    float s2 = part[base * 2 + 1]        + part[(base + 256) * 2 + 1]
             + part[(base + 512) * 2 + 1] + part[(base + 768) * 2 + 1];
    #pragma unroll
    for (int o = 32; o > 0; o >>= 1) {
        s  += __shfl_down(s, o);
        s2 += __shfl_down(s2, o);
    }
    int wave = t >> 6, lane = t & 63;
    if (lane == 0) { ls[wave][0] = s; ls[wave][1] = s2; }
    __syncthreads();
    if (t == 0) {
        float a = 0.f, c = 0.f;
        #pragma unroll
        for (int i = 0; i < 4; i++) { a += ls[i][0]; c += ls[i][1]; }
        const float n = (float)(Cc * HW);
        float m = a / n;
        float var = c / n - m * m;
        s_ms[0] = m;
        s_ms[1] = rsqrtf(var + EPSf);
    }
    __syncthreads();
    m_out = s_ms[0];
    rs_out = s_ms[1];
}

// ---- block-1 finalize: GN-stats + normalize+ReLU+residual -> h1 + hnh ----
__global__ __launch_bounds__(256)
void gn_fin1_kernel(const float* __restrict__ y, const float* __restrict__ res,
                    const float* __restrict__ g, const float* __restrict__ be,
                    const float* __restrict__ part, float* __restrict__ h1,
                    ushort* __restrict__ hnh) {
    __shared__ float s_t[64][65];
    int blk = blockIdx.x;                 // Bz * (HW/64) = 1024
    int p0 = (blk & 255) * 64;
    int b = blk >> 8;
    int t = threadIdx.x;
    int tp = t & 63;
    float m, rs;
    gn_reduce_stats(part, b, t, m, rs);
    #pragma unroll
    for (int i = 0; i < 16; i++) {
        int c = i * 4 + (t >> 6);
        size_t idx = ((size_t)(b * 64 + c)) * HW + p0 + tp;
        float v = (y[idx] - m) * rs * g[c] + be[c];
        v = fmaxf(v, 0.f) + res[idx];
        h1[idx] = v;
        s_t[c][tp] = v;
    }
    __syncthreads();
    #pragma unroll
    for (int i = 0; i < 16; i++) {
        int pl = i * 4 + (t >> 6);
        hnh[((size_t)b * HW + p0 + pl) * 64 + tp] = f32_to_bf16(s_t[tp][pl]);
    }
}

// ---- block-2 finalize: GN-stats + normalize + ReLU + residual -> out ----
__global__ __launch_bounds__(256)
void gn_fin2_kernel(const float* __restrict__ y, const float* __restrict__ res,
                    const float* __restrict__ g, const float* __restrict__ be,
                    const float* __restrict__ part, float* __restrict__ out) {
    int idx = (blockIdx.x * 256 + threadIdx.x) * 4;   // B*C*H*W / 4 threads
    int c = (idx >> 14) & 63;
    int b = idx >> 20;
    float m, rs;
    gn_reduce_stats(part, b, threadIdx.x, m, rs);
    float gc = g[c], bc = be[c];
    float4 yv = *reinterpret_cast<const float4*>(y + idx);
    float4 rv = *reinterpret_cast<const float4*>(res + idx);
    float4 o;
    o.x = fmaxf((yv.x - m) * rs * gc + bc, 0.f) + rv.x;
    o.y = fmaxf((yv.y - m) * rs * gc + bc, 0.f) + rv.y;
    o.z = fmaxf((yv.z - m) * rs * gc + bc, 0.f) + rv.z;
    o.w = fmaxf((yv.w - m) * rs * gc + bc, 0.f) + rv.w;
    *reinterpret_cast<float4*>(out + idx) = o;
}

extern "C" void kernel_launch(void* const* d_in, const int* in_sizes, int n_in,
                              void* d_out, int out_size, void* d_ws, size_t ws_size,
                              hipStream_t stream) {
    const float* x   = (const float*)d_in[0];
    const float* w1  = (const float*)d_in[1];
    const float* b1  = (const float*)d_in[2];
    const float* ow1 = (const float*)d_in[3];
    const float* ob1 = (const float*)d_in[4];
    const float* g1  = (const float*)d_in[5];
    const float* be1 = (const float*)d_in[6];
    const float* w2  = (const float*)d_in[7];
    const float* b2  = (const float*)d_in[8];
    const float* ow2 = (const float*)d_in[9];
    const float* ob2 = (const float*)d_in[10];
    const float* g2  = (const float*)d_in[11];
    const float* be2 = (const float*)d_in[12];
    float* out = (float*)d_out;

    float* ws    = (float*)d_ws;
    float* ybuf  = ws;                                   // 4,194,304 f
    float* h1    = ybuf + (size_t)Bz * Cc * HW;          // 4,194,304 f
    ushort* xnh  = (ushort*)(h1 + (size_t)Bz * Cc * HW); // 4,194,304 bf16
    ushort* hnh  = xnh + (size_t)Bz * HW * 64;           // 4,194,304 bf16
    ushort* wA1  = hnh + (size_t)Bz * HW * 64;           // 36,864 bf16
    ushort* wA2  = wA1 + 36864;                          // 36,864 bf16
    ushort* owA1 = wA2 + 36864;                          // 18,432 bf16
    ushort* owA2 = owA1 + 18432;                         // 18,432 bf16
    float* part  = (float*)(owA2 + 18432);               // 8192 f

    frag_kernel<<<(110592 + 255) / 256, 256, 0, stream>>>(w1, w2, ow1, ow2, wA1, wA2, owA1, owA2);
    nhwc_kernel<<<Bz * (HW / 64), 256, 0, stream>>>(x, xnh);

    // block 1: fused wave-per-16px kernel -> fin1
    deform_fused_kernel<<<1024, 256, 0, stream>>>(xnh, wA1, owA1, b1, ob1, ybuf, part);
    gn_fin1_kernel<<<Bz * (HW / 64), 256, 0, stream>>>(ybuf, x, g1, be1, part, h1, hnh);

    // block 2: same, residual on h1, finalize to out
    deform_fused_kernel<<<1024, 256, 0, stream>>>(hnh, wA2, owA2, b2, ob2, ybuf, part);
    gn_fin2_kernel<<<Bz * Cc * HW / 1024, 256, 0, stream>>>(ybuf, h1, g2, be2, part, out);
}